// Round 1
// baseline (577.791 us; speedup 1.0000x reference)
//
#include <hip/hip_runtime.h>

#define DEVI __device__ __forceinline__

typedef __attribute__((ext_vector_type(4))) float f32x4;
typedef __attribute__((ext_vector_type(8))) short bf16x8;

static constexpr int NT = 2048;   // tokens
static constexpr int CD = 2048;   // model dim
static constexpr int NE = 8;      // experts
static constexpr int ID = 1408;   // expert ffn dim
static constexpr int SD = 2816;   // shared ffn dim
static constexpr int ROWS = 2 * NT;        // total routed (token,slot) rows
static constexpr int ROWS_PAD = ROWS + 128;

DEVI unsigned short f2bf(float f) {
  unsigned u = __builtin_bit_cast(unsigned, f);
  u += 0x7fff + ((u >> 16) & 1);           // round-to-nearest-even
  return (unsigned short)(u >> 16);
}
DEVI float silu_f(float z) { return z / (1.f + __expf(-z)); }

// ---------------- router: logits, top-2, softmax, per-expert positions ----
__global__ __launch_bounds__(64) void k_router(const float* __restrict__ x,
    const float* __restrict__ gw, int* __restrict__ counts,
    int* __restrict__ eidx, int* __restrict__ posn, float* __restrict__ probs)
{
  const int n = blockIdx.x;
  const int lane = threadIdx.x;
  const float4* xr = (const float4*)(x + (size_t)n * CD);
  float acc[NE];
#pragma unroll
  for (int e = 0; e < NE; ++e) acc[e] = 0.f;
  for (int i = lane; i < CD / 4; i += 64) {
    float4 xv = xr[i];
#pragma unroll
    for (int e = 0; e < NE; ++e) {
      float4 gv = ((const float4*)(gw + (size_t)e * CD))[i];
      acc[e] += xv.x * gv.x + xv.y * gv.y + xv.z * gv.z + xv.w * gv.w;
    }
  }
#pragma unroll
  for (int e = 0; e < NE; ++e) {
    float v = acc[e];
#pragma unroll
    for (int off = 32; off > 0; off >>= 1) v += __shfl_down(v, off);
    acc[e] = v;
  }
  if (lane == 0) {
    int b0 = 0; float m0 = acc[0];
#pragma unroll
    for (int e = 1; e < NE; ++e) if (acc[e] > m0) { m0 = acc[e]; b0 = e; }
    int b1 = -1; float m1 = 0.f;
#pragma unroll
    for (int e = 0; e < NE; ++e) {
      if (e == b0) continue;
      if (b1 < 0 || acc[e] > m1) { m1 = acc[e]; b1 = e; }
    }
    float d = __expf(m1 - m0);
    float inv = 1.f / (1.f + d);
    eidx[2 * n] = b0; eidx[2 * n + 1] = b1;
    probs[2 * n] = inv; probs[2 * n + 1] = d * inv;
    posn[2 * n] = atomicAdd(&counts[b0], 1);
    posn[2 * n + 1] = atomicAdd(&counts[b1], 1);
  }
}

__global__ void k_scan(const int* __restrict__ counts, int* __restrict__ bases) {
  if (threadIdx.x == 0) {
    int s = 0;
    for (int e = 0; e < NE; ++e) { bases[e] = s; s += counts[e]; }
  }
}

__global__ __launch_bounds__(256) void k_build(const int* __restrict__ eidx,
    const int* __restrict__ posn, const int* __restrict__ bases,
    int* __restrict__ rows_of, int* __restrict__ row2tok)
{
  int n = blockIdx.x * 256 + threadIdx.x;
  if (n >= NT) return;
#pragma unroll
  for (int k = 0; k < 2; ++k) {
    int e = eidx[2 * n + k];
    int row = bases[e] + posn[2 * n + k];
    rows_of[2 * n + k] = row;
    row2tok[row] = n;
  }
}

// ---------------- tiled MFMA GEMM (O = A @ B^T), 4 modes --------------------
// MODE 0: routed up   : A = gathered x rows (f32->bf16), B = w1&w3, epi silu -> h(bf16)
// MODE 1: routed down : A = h (bf16), B = w2[e] (f32->bf16), epi -> eo(f32)
// MODE 2: shared up   : A = x (f32->bf16), B = sw1&sw3, epi silu -> hs(bf16)
// MODE 3: shared down : A = hs (bf16), B = sw2, epi + top2 combine -> y(f32)
struct GArgs {
  const float* Af;
  const unsigned short* Ab;
  const float* B1; const float* B3;
  void* Out;
  const int* counts; const int* bases; const int* row2tok;
  const int* rows_of; const float* probs; const float* eo;
};

template<int MODE>
__global__ __launch_bounds__(256) void k_gemm(GArgs a)
{
  constexpr bool DUAL = (MODE == 0 || MODE == 2);
  constexpr bool ABF  = (MODE == 1 || MODE == 3);
  constexpr int BM = (MODE == 3) ? 64 : 128;
  constexpr int BN = DUAL ? 64 : 128;
  constexpr int KD = (MODE == 0 || MODE == 2) ? CD : (MODE == 1 ? ID : SD);
  constexpr int MF = BM / 32;      // 16-row frags per wave (waves 2x2)
  constexpr int NF = BN / 32;
  constexpr int KGS_A = (BM + 2) * 16;   // kgroup stride (bytes), == 32 mod 128
  constexpr int KGS_B = (BN + 2) * 16;
  constexpr int AIT = ABF ? BM / 64 : BM / 32;
  constexpr int BIT = BN / 32;

  __shared__ __align__(16) char smem[4 * KGS_A + (DUAL ? 2 : 1) * 4 * KGS_B];
  char* sA  = smem;
  char* sB1 = smem + 4 * KGS_A;
  char* sB3 = sB1 + 4 * KGS_B;

  const int e = blockIdx.z;
  int M, baserow;
  if constexpr (MODE == 0 || MODE == 1) {
    int ne = a.counts[e];
    if ((int)(blockIdx.y * BM) >= ne) return;
    M = ne; baserow = a.bases[e];
  } else { M = NT; baserow = 0; }
  const int m0 = blockIdx.y * BM;
  const int n0 = blockIdx.x * BN;
  const int tid = threadIdx.x;

  const float* Bb1; const float* Bb3 = nullptr;
  if constexpr (MODE == 0)      { Bb1 = a.B1 + ((size_t)e * ID + n0) * CD; Bb3 = a.B3 + ((size_t)e * ID + n0) * CD; }
  else if constexpr (MODE == 1) { Bb1 = a.B1 + ((size_t)e * CD + n0) * ID; }
  else if constexpr (MODE == 2) { Bb1 = a.B1 + (size_t)n0 * CD; Bb3 = a.B3 + (size_t)n0 * CD; }
  else                          { Bb1 = a.B1 + (size_t)n0 * SD; }

  const float* arf[AIT];
  const unsigned short* arb[AIT];
  if constexpr (!ABF) {
    int cc = (tid & 7) * 4;
#pragma unroll
    for (int it = 0; it < AIT; ++it) {
      int r = (tid >> 3) + 32 * it;
      int grow = m0 + r;
      const float* base;
      if constexpr (MODE == 0) {
        int tok = (grow < M) ? a.row2tok[baserow + grow] : 0;
        base = a.Af + (size_t)tok * CD;
      } else {
        base = a.Af + (size_t)grow * CD;
      }
      arf[it] = base + cc;
    }
  } else {
#pragma unroll
    for (int it = 0; it < AIT; ++it) {
      int r = (tid >> 2) + 64 * it;
      size_t row = (MODE == 1) ? (size_t)(baserow + m0 + r) : (size_t)(m0 + r);
      arb[it] = a.Ab + row * KD + (tid & 3) * 8;
    }
  }
  const float* brf1[BIT]; const float* brf3[BIT];
  {
    int cc = (tid & 7) * 4;
#pragma unroll
    for (int it = 0; it < BIT; ++it) {
      int r = (tid >> 3) + 32 * it;
      brf1[it] = Bb1 + (size_t)r * KD + cc;
      if constexpr (DUAL) brf3[it] = Bb3 + (size_t)r * KD + cc;
    }
  }

  f32x4 acc1[MF][NF]; f32x4 acc3[MF][NF];
#pragma unroll
  for (int m = 0; m < MF; ++m)
#pragma unroll
    for (int n = 0; n < NF; ++n) {
      acc1[m][n] = {0.f, 0.f, 0.f, 0.f};
      if constexpr (DUAL) acc3[m][n] = {0.f, 0.f, 0.f, 0.f};
    }

  const int lane = tid & 63;
  const int wv = tid >> 6;
  const int wr = wv >> 1, wc = wv & 1;
  const int lrow = lane & 15, lkg = lane >> 4;
  const int dkg = (tid & 7) >> 1;
  const int dhalf = (tid & 1) * 8;

  for (int k0 = 0; k0 < KD; k0 += 32) {
    __syncthreads();
    if constexpr (!ABF) {
#pragma unroll
      for (int it = 0; it < AIT; ++it) {
        int r = (tid >> 3) + 32 * it;
        float4 v = *(const float4*)(arf[it] + k0);
        ushort4 pk = make_ushort4(f2bf(v.x), f2bf(v.y), f2bf(v.z), f2bf(v.w));
        *(ushort4*)(sA + dkg * KGS_A + r * 16 + dhalf) = pk;
      }
    } else {
#pragma unroll
      for (int it = 0; it < AIT; ++it) {
        int r = (tid >> 2) + 64 * it;
        int4 v = *(const int4*)(arb[it] + k0);
        *(int4*)(sA + (tid & 3) * KGS_A + r * 16) = v;
      }
    }
#pragma unroll
    for (int it = 0; it < BIT; ++it) {
      int r = (tid >> 3) + 32 * it;
      float4 v = *(const float4*)(brf1[it] + k0);
      ushort4 pk = make_ushort4(f2bf(v.x), f2bf(v.y), f2bf(v.z), f2bf(v.w));
      *(ushort4*)(sB1 + dkg * KGS_B + r * 16 + dhalf) = pk;
      if constexpr (DUAL) {
        float4 v3 = *(const float4*)(brf3[it] + k0);
        ushort4 pk3 = make_ushort4(f2bf(v3.x), f2bf(v3.y), f2bf(v3.z), f2bf(v3.w));
        *(ushort4*)(sB3 + dkg * KGS_B + r * 16 + dhalf) = pk3;
      }
    }
    __syncthreads();

    bf16x8 af[MF], bv1[NF], bv3[NF];
#pragma unroll
    for (int m = 0; m < MF; ++m)
      af[m] = *(const bf16x8*)(sA + lkg * KGS_A + (wr * (MF * 16) + m * 16 + lrow) * 16);
#pragma unroll
    for (int n = 0; n < NF; ++n) {
      bv1[n] = *(const bf16x8*)(sB1 + lkg * KGS_B + (wc * (NF * 16) + n * 16 + lrow) * 16);
      if constexpr (DUAL)
        bv3[n] = *(const bf16x8*)(sB3 + lkg * KGS_B + (wc * (NF * 16) + n * 16 + lrow) * 16);
    }
#pragma unroll
    for (int m = 0; m < MF; ++m)
#pragma unroll
      for (int n = 0; n < NF; ++n) {
        acc1[m][n] = __builtin_amdgcn_mfma_f32_16x16x32_bf16(af[m], bv1[n], acc1[m][n], 0, 0, 0);
        if constexpr (DUAL)
          acc3[m][n] = __builtin_amdgcn_mfma_f32_16x16x32_bf16(af[m], bv3[n], acc3[m][n], 0, 0, 0);
      }
  }

  // epilogue
#pragma unroll
  for (int m = 0; m < MF; ++m) {
    int rbase = m0 + wr * (MF * 16) + m * 16 + lkg * 4;
#pragma unroll
    for (int j = 0; j < 4; ++j) {
      int grow = rbase + j;
      if constexpr (MODE == 0 || MODE == 1) { if (grow >= M) continue; }
      int r0 = 0, r1 = 0; float p0 = 0.f, p1 = 0.f;
      if constexpr (MODE == 3) {
        r0 = a.rows_of[2 * grow]; r1 = a.rows_of[2 * grow + 1];
        p0 = a.probs[2 * grow];   p1 = a.probs[2 * grow + 1];
      }
#pragma unroll
      for (int n = 0; n < NF; ++n) {
        int gcol = n0 + wc * (NF * 16) + n * 16 + lrow;
        float v1 = acc1[m][n][j];
        if constexpr (MODE == 0) {
          float hh = silu_f(v1) * acc3[m][n][j];
          ((unsigned short*)a.Out)[(size_t)(baserow + grow) * ID + gcol] = f2bf(hh);
        } else if constexpr (MODE == 1) {
          ((float*)a.Out)[(size_t)(baserow + grow) * CD + gcol] = v1;
        } else if constexpr (MODE == 2) {
          float hh = silu_f(v1) * acc3[m][n][j];
          ((unsigned short*)a.Out)[(size_t)grow * SD + gcol] = f2bf(hh);
        } else {
          float vv = v1 + p0 * a.eo[(size_t)r0 * CD + gcol] + p1 * a.eo[(size_t)r1 * CD + gcol];
          ((float*)a.Out)[(size_t)grow * CD + gcol] = vv;
        }
      }
    }
  }
}

// ---------------- launch ---------------------------------------------------
extern "C" void kernel_launch(void* const* d_in, const int* in_sizes, int n_in,
                              void* d_out, int out_size, void* d_ws, size_t ws_size,
                              hipStream_t stream)
{
  const float* x   = (const float*)d_in[0];
  const float* gw  = (const float*)d_in[1];
  const float* w1  = (const float*)d_in[2];
  const float* w3  = (const float*)d_in[3];
  const float* w2  = (const float*)d_in[4];
  const float* sw1 = (const float*)d_in[5];
  const float* sw3 = (const float*)d_in[6];
  const float* sw2 = (const float*)d_in[7];
  float* y = (float*)d_out;

  char* p = (char*)d_ws;
  auto alloc = [&](size_t b) { char* r = p; p += (b + 255) & ~(size_t)255; return r; };
  int*   counts  = (int*)alloc(NE * 4);
  int*   bases   = (int*)alloc(NE * 4);
  int*   eidx    = (int*)alloc((size_t)NT * 2 * 4);
  int*   posn    = (int*)alloc((size_t)NT * 2 * 4);
  float* probs   = (float*)alloc((size_t)NT * 2 * 4);
  int*   rows_of = (int*)alloc((size_t)NT * 2 * 4);
  int*   row2tok = (int*)alloc((size_t)ROWS * 4);
  unsigned short* h  = (unsigned short*)alloc((size_t)ROWS_PAD * ID * 2);
  float*          eo = (float*)alloc((size_t)ROWS_PAD * CD * 4);
  unsigned short* hs = (unsigned short*)alloc((size_t)NT * SD * 2);

  hipMemsetAsync(counts, 0, NE * 4, stream);
  k_router<<<NT, 64, 0, stream>>>(x, gw, counts, eidx, posn, probs);
  k_scan<<<1, 64, 0, stream>>>(counts, bases);
  k_build<<<NT / 256, 256, 0, stream>>>(eidx, posn, bases, rows_of, row2tok);

  {
    GArgs g{}; g.Af = x; g.B1 = sw1; g.B3 = sw3; g.Out = hs;
    k_gemm<2><<<dim3(SD / 64, NT / 128, 1), 256, 0, stream>>>(g);
  }
  {
    GArgs g{}; g.Af = x; g.B1 = w1; g.B3 = w3; g.Out = h;
    g.counts = counts; g.bases = bases; g.row2tok = row2tok;
    k_gemm<0><<<dim3(ID / 64, NT / 128, NE), 256, 0, stream>>>(g);
  }
  {
    GArgs g{}; g.Ab = h; g.B1 = w2; g.Out = eo;
    g.counts = counts; g.bases = bases;
    k_gemm<1><<<dim3(CD / 128, NT / 128, NE), 256, 0, stream>>>(g);
  }
  {
    GArgs g{}; g.Ab = hs; g.B1 = sw2; g.Out = y;
    g.rows_of = rows_of; g.probs = probs; g.eo = eo;
    k_gemm<3><<<dim3(CD / 128, NT / 64, 1), 256, 0, stream>>>(g);
  }
}

// Round 2
// 568.658 us; speedup vs baseline: 1.0161x; 1.0161x over previous
//
#include <hip/hip_runtime.h>

#define DEVI __device__ __forceinline__

typedef __attribute__((ext_vector_type(4))) float f32x4;
typedef __attribute__((ext_vector_type(8))) short bf16x8;

static constexpr int NT = 2048;   // tokens
static constexpr int CD = 2048;   // model dim
static constexpr int NE = 8;      // experts
static constexpr int ID = 1408;   // expert ffn dim
static constexpr int SD = 2816;   // shared ffn dim
static constexpr int ROWS = 2 * NT;
static constexpr int ROWS_PAD = ROWS + 128;

DEVI unsigned short f2bf(float f) {
  unsigned u = __builtin_bit_cast(unsigned, f);
  u += 0x7fff + ((u >> 16) & 1);           // RNE
  return (unsigned short)(u >> 16);
}
DEVI float bf2f(unsigned short s) { return __builtin_bit_cast(float, (unsigned)s << 16); }
DEVI float silu_f(float z) { return z / (1.f + __expf(-z)); }

DEVI void gll16(const void* g, void* l) {
  __builtin_amdgcn_global_load_lds((__attribute__((address_space(1))) void*)(void*)g,
                                   (__attribute__((address_space(3))) void*)l, 16, 0, 0);
}

// ---------------- fp32 -> bf16 convert (vectorized, grid-stride) -----------
__global__ __launch_bounds__(256) void k_cvt(const float* __restrict__ s,
                                             unsigned short* __restrict__ d, int n8)
{
  int i = blockIdx.x * 256 + threadIdx.x;
  int stride = gridDim.x * 256;
  for (; i < n8; i += stride) {
    float4 a = ((const float4*)s)[2 * i];
    float4 b = ((const float4*)s)[2 * i + 1];
    ushort4 p0 = make_ushort4(f2bf(a.x), f2bf(a.y), f2bf(a.z), f2bf(a.w));
    ushort4 p1 = make_ushort4(f2bf(b.x), f2bf(b.y), f2bf(b.z), f2bf(b.w));
    ((ushort4*)d)[2 * i]     = p0;
    ((ushort4*)d)[2 * i + 1] = p1;
  }
}

// ---------------- router ---------------------------------------------------
__global__ __launch_bounds__(64) void k_router(const float* __restrict__ x,
    const float* __restrict__ gw, int* __restrict__ counts,
    int* __restrict__ eidx, int* __restrict__ posn, float* __restrict__ probs)
{
  const int n = blockIdx.x;
  const int lane = threadIdx.x;
  const float4* xr = (const float4*)(x + (size_t)n * CD);
  float acc[NE];
#pragma unroll
  for (int e = 0; e < NE; ++e) acc[e] = 0.f;
  for (int i = lane; i < CD / 4; i += 64) {
    float4 xv = xr[i];
#pragma unroll
    for (int e = 0; e < NE; ++e) {
      float4 gv = ((const float4*)(gw + (size_t)e * CD))[i];
      acc[e] += xv.x * gv.x + xv.y * gv.y + xv.z * gv.z + xv.w * gv.w;
    }
  }
#pragma unroll
  for (int e = 0; e < NE; ++e) {
    float v = acc[e];
#pragma unroll
    for (int off = 32; off > 0; off >>= 1) v += __shfl_down(v, off);
    acc[e] = v;
  }
  if (lane == 0) {
    int b0 = 0; float m0 = acc[0];
#pragma unroll
    for (int e = 1; e < NE; ++e) if (acc[e] > m0) { m0 = acc[e]; b0 = e; }
    int b1 = -1; float m1 = 0.f;
#pragma unroll
    for (int e = 0; e < NE; ++e) {
      if (e == b0) continue;
      if (b1 < 0 || acc[e] > m1) { m1 = acc[e]; b1 = e; }
    }
    float d = __expf(m1 - m0);
    float inv = 1.f / (1.f + d);
    eidx[2 * n] = b0; eidx[2 * n + 1] = b1;
    probs[2 * n] = inv; probs[2 * n + 1] = d * inv;
    posn[2 * n] = atomicAdd(&counts[b0], 1);
    posn[2 * n + 1] = atomicAdd(&counts[b1], 1);
  }
}

__global__ void k_scan(const int* __restrict__ counts, int* __restrict__ bases) {
  if (threadIdx.x == 0) {
    int s = 0;
    for (int e = 0; e < NE; ++e) { bases[e] = s; s += counts[e]; }
  }
}

__global__ __launch_bounds__(256) void k_build(const int* __restrict__ eidx,
    const int* __restrict__ posn, const int* __restrict__ bases,
    int* __restrict__ rows_of, int* __restrict__ row2tok)
{
  int n = blockIdx.x * 256 + threadIdx.x;
  if (n >= NT) return;
#pragma unroll
  for (int k = 0; k < 2; ++k) {
    int e = eidx[2 * n + k];
    int row = bases[e] + posn[2 * n + k];
    rows_of[2 * n + k] = row;
    row2tok[row] = n;
  }
}

// ---------------- MFMA GEMM, all-bf16 inputs, global_load_lds + XOR swizzle -
// O = A @ B^T. BM=128, BK=64, 4 waves (2x2). LDS rows of 128B; element (r,k)
// at byte r*128 + (((k>>3)^(r&7))*16) + (k&7)*2. Staging writes LDS linearly
// (lane*16) with the inverse slot permutation applied to the GLOBAL source
// (stays within the row's 128B line -> coalescing preserved).
// MODE 0: routed up   : A=xb gathered, B=w1b,w3b[e], epi silu -> h (bf16)
// MODE 1: routed down : A=h,  B=w2b[e],              epi -> eo (bf16)
// MODE 2: shared up   : A=xb, B=sw1b,sw3b,           epi silu -> hs (bf16)
// MODE 3: shared down : A=hs, B=sw2b, epi + top2 combine(eo) -> y (f32)
struct GArgs {
  const unsigned short* A;
  const unsigned short* B1; const unsigned short* B3;
  void* Out;
  const int* counts; const int* bases; const int* row2tok;
  const int* rows_of; const float* probs; const unsigned short* eo;
};

template<int MODE>
__global__ __launch_bounds__(256) void k_gemm(GArgs a)
{
  constexpr bool DUAL = (MODE == 0 || MODE == 2);
  constexpr int BM = 128;
  constexpr int BN = DUAL ? 64 : 128;
  constexpr int KD = (MODE == 0 || MODE == 2) ? CD : (MODE == 1 ? ID : SD);
  constexpr int NH = BN / 2;        // per-wave col extent
  constexpr int NFT = NH / 16;      // 2 (dual) or 4 (single)
  constexpr int BT = DUAL ? 2 : 4;  // B staging instrs per wave per matrix

  __shared__ __align__(16) char sm[32768];
  char* sA  = sm;                 // 128 rows * 128B = 16KB
  char* sB1 = sm + 16384;         // BN rows * 128B
  char* sB3 = sm + 16384 + 8192;  // (dual only) 64 rows * 128B

  const int e = blockIdx.z;
  int M, baserow = 0;
  if constexpr (MODE <= 1) {
    int ne = a.counts[e];
    if ((int)(blockIdx.x * BM) >= ne) return;
    M = ne; baserow = a.bases[e];
  } else { M = NT; }
  const int m0 = blockIdx.x * BM;   // m-fastest: consecutive blocks share B panel
  const int n0 = blockIdx.y * BN;

  const unsigned short* B1;
  const unsigned short* B3 = nullptr;
  if constexpr (MODE == 0)      { B1 = a.B1 + ((size_t)e * ID + n0) * CD; B3 = a.B3 + ((size_t)e * ID + n0) * CD; }
  else if constexpr (MODE == 1) { B1 = a.B1 + ((size_t)e * CD + n0) * ID; }
  else if constexpr (MODE == 2) { B1 = a.B1 + (size_t)n0 * CD; B3 = a.B3 + (size_t)n0 * CD; }
  else                          { B1 = a.B1 + (size_t)n0 * SD; }

  const int tid = threadIdx.x, l = tid & 63, w = tid >> 6;
  const int wr = w >> 1, wc = w & 1;
  const int slot = ((l & 7) ^ ((l >> 3) & 7)) * 16;   // pre-swizzled global slot (bytes)

  const char* aP[4];
#pragma unroll
  for (int t = 0; t < 4; ++t) {
    int r = w * 32 + t * 8 + (l >> 3);
    const unsigned short* rb;
    if constexpr (MODE == 0) {
      int grow = m0 + r; int gr = grow < M ? grow : 0;
      rb = a.A + (size_t)a.row2tok[baserow + gr] * CD;
    } else if constexpr (MODE == 1) {
      rb = a.A + (size_t)(baserow + m0 + r) * KD;
    } else {
      rb = a.A + (size_t)(m0 + r) * KD;
    }
    aP[t] = (const char*)rb + slot;
  }
  const char* bP1[BT]; const char* bP3[BT];
#pragma unroll
  for (int t = 0; t < BT; ++t) {
    int r = w * (8 * BT) + t * 8 + (l >> 3);
    bP1[t] = (const char*)(B1 + (size_t)r * KD) + slot;
    if constexpr (DUAL) bP3[t] = (const char*)(B3 + (size_t)r * KD) + slot;
  }

  f32x4 acc1[4][NFT]; f32x4 acc3[4][NFT];
#pragma unroll
  for (int m = 0; m < 4; ++m)
#pragma unroll
    for (int n = 0; n < NFT; ++n) {
      acc1[m][n] = {0.f, 0.f, 0.f, 0.f};
      if constexpr (DUAL) acc3[m][n] = {0.f, 0.f, 0.f, 0.f};
    }

  const int lrow = l & 15, lkg = l >> 4, l7 = l & 7;
  const int ao0 = (lkg ^ l7) * 16;        // kk=0 swizzled kgroup slot
  const int ao1 = ((4 + lkg) ^ l7) * 16;  // kk=1

  for (int k0 = 0; k0 < KD; k0 += 64) {
    __syncthreads();
    size_t kb = (size_t)k0 * 2;
#pragma unroll
    for (int t = 0; t < 4; ++t) gll16(aP[t] + kb, sA + (w * 4 + t) * 1024);
#pragma unroll
    for (int t = 0; t < BT; ++t) {
      gll16(bP1[t] + kb, sB1 + (w * BT + t) * 1024);
      if constexpr (DUAL) gll16(bP3[t] + kb, sB3 + (w * BT + t) * 1024);
    }
    __syncthreads();
#pragma unroll
    for (int kk = 0; kk < 2; ++kk) {
      const int ao = kk ? ao1 : ao0;
      bf16x8 af[4];
#pragma unroll
      for (int m = 0; m < 4; ++m)
        af[m] = *(const bf16x8*)(sA + (wr * 64 + m * 16 + lrow) * 128 + ao);
#pragma unroll
      for (int n = 0; n < NFT; ++n) {
        bf16x8 b1 = *(const bf16x8*)(sB1 + (wc * NH + n * 16 + lrow) * 128 + ao);
        bf16x8 b3;
        if constexpr (DUAL)
          b3 = *(const bf16x8*)(sB3 + (wc * NH + n * 16 + lrow) * 128 + ao);
#pragma unroll
        for (int m = 0; m < 4; ++m) {
          acc1[m][n] = __builtin_amdgcn_mfma_f32_16x16x32_bf16(af[m], b1, acc1[m][n], 0, 0, 0);
          if constexpr (DUAL)
            acc3[m][n] = __builtin_amdgcn_mfma_f32_16x16x32_bf16(af[m], b3, acc3[m][n], 0, 0, 0);
        }
      }
    }
  }

  // epilogue (C/D: col = lane&15, row = (lane>>4)*4 + reg — m89-verified)
#pragma unroll
  for (int m = 0; m < 4; ++m) {
    int rbase = m0 + wr * 64 + m * 16 + lkg * 4;
#pragma unroll
    for (int j = 0; j < 4; ++j) {
      int grow = rbase + j;
      if constexpr (MODE <= 1) { if (grow >= M) continue; }
      int r0 = 0, r1 = 0; float p0 = 0.f, p1 = 0.f;
      if constexpr (MODE == 3) {
        r0 = a.rows_of[2 * grow]; r1 = a.rows_of[2 * grow + 1];
        p0 = a.probs[2 * grow];   p1 = a.probs[2 * grow + 1];
      }
#pragma unroll
      for (int n = 0; n < NFT; ++n) {
        int gcol = n0 + wc * NH + n * 16 + lrow;
        float v1 = acc1[m][n][j];
        if constexpr (MODE == 0) {
          float hh = silu_f(v1) * acc3[m][n][j];
          ((unsigned short*)a.Out)[(size_t)(baserow + grow) * ID + gcol] = f2bf(hh);
        } else if constexpr (MODE == 1) {
          ((unsigned short*)a.Out)[(size_t)(baserow + grow) * CD + gcol] = f2bf(v1);
        } else if constexpr (MODE == 2) {
          float hh = silu_f(v1) * acc3[m][n][j];
          ((unsigned short*)a.Out)[(size_t)grow * SD + gcol] = f2bf(hh);
        } else {
          float vv = v1 + p0 * bf2f(a.eo[(size_t)r0 * CD + gcol]) + p1 * bf2f(a.eo[(size_t)r1 * CD + gcol]);
          ((float*)a.Out)[(size_t)grow * CD + gcol] = vv;
        }
      }
    }
  }
}

// ---------------- launch ---------------------------------------------------
extern "C" void kernel_launch(void* const* d_in, const int* in_sizes, int n_in,
                              void* d_out, int out_size, void* d_ws, size_t ws_size,
                              hipStream_t stream)
{
  const float* x   = (const float*)d_in[0];
  const float* gw  = (const float*)d_in[1];
  const float* w1  = (const float*)d_in[2];
  const float* w3  = (const float*)d_in[3];
  const float* w2  = (const float*)d_in[4];
  const float* sw1 = (const float*)d_in[5];
  const float* sw3 = (const float*)d_in[6];
  const float* sw2 = (const float*)d_in[7];
  float* y = (float*)d_out;

  char* p = (char*)d_ws;
  auto alloc = [&](size_t b) { char* r = p; p += (b + 255) & ~(size_t)255; return r; };
  int*   counts  = (int*)alloc(NE * 4);
  int*   bases   = (int*)alloc(NE * 4);
  int*   eidx    = (int*)alloc((size_t)NT * 2 * 4);
  int*   posn    = (int*)alloc((size_t)NT * 2 * 4);
  float* probs   = (float*)alloc((size_t)NT * 2 * 4);
  int*   rows_of = (int*)alloc((size_t)NT * 2 * 4);
  int*   row2tok = (int*)alloc((size_t)ROWS * 4);
  unsigned short* xb   = (unsigned short*)alloc((size_t)NT * CD * 2);
  unsigned short* w1b  = (unsigned short*)alloc((size_t)NE * ID * CD * 2);
  unsigned short* w3b  = (unsigned short*)alloc((size_t)NE * ID * CD * 2);
  unsigned short* w2b  = (unsigned short*)alloc((size_t)NE * CD * ID * 2);
  unsigned short* sw1b = (unsigned short*)alloc((size_t)SD * CD * 2);
  unsigned short* sw3b = (unsigned short*)alloc((size_t)SD * CD * 2);
  unsigned short* sw2b = (unsigned short*)alloc((size_t)CD * SD * 2);
  unsigned short* h    = (unsigned short*)alloc((size_t)ROWS_PAD * ID * 2);
  unsigned short* eo   = (unsigned short*)alloc((size_t)ROWS_PAD * CD * 2);
  unsigned short* hs   = (unsigned short*)alloc((size_t)NT * SD * 2);

  hipMemsetAsync(counts, 0, NE * 4, stream);

  auto cvt = [&](const float* s, unsigned short* d, size_t n) {
    int n8 = (int)(n / 8);
    int grid = (n8 + 255) / 256; if (grid > 2048) grid = 2048;
    k_cvt<<<grid, 256, 0, stream>>>(s, d, n8);
  };
  cvt(x,   xb,   (size_t)NT * CD);
  cvt(w1,  w1b,  (size_t)NE * ID * CD);
  cvt(w3,  w3b,  (size_t)NE * ID * CD);
  cvt(w2,  w2b,  (size_t)NE * CD * ID);
  cvt(sw1, sw1b, (size_t)SD * CD);
  cvt(sw3, sw3b, (size_t)SD * CD);
  cvt(sw2, sw2b, (size_t)CD * SD);

  k_router<<<NT, 64, 0, stream>>>(x, gw, counts, eidx, posn, probs);
  k_scan<<<1, 64, 0, stream>>>(counts, bases);
  k_build<<<NT / 256, 256, 0, stream>>>(eidx, posn, bases, rows_of, row2tok);

  {
    GArgs g{}; g.A = xb; g.B1 = sw1b; g.B3 = sw3b; g.Out = hs;
    k_gemm<2><<<dim3(NT / 128, SD / 64, 1), 256, 0, stream>>>(g);
  }
  {
    GArgs g{}; g.A = xb; g.B1 = w1b; g.B3 = w3b; g.Out = h;
    g.counts = counts; g.bases = bases; g.row2tok = row2tok;
    k_gemm<0><<<dim3(NT / 128, ID / 64, NE), 256, 0, stream>>>(g);
  }
  {
    GArgs g{}; g.A = h; g.B1 = w2b; g.Out = eo;
    g.counts = counts; g.bases = bases;
    k_gemm<1><<<dim3(NT / 128, CD / 128, NE), 256, 0, stream>>>(g);
  }
  {
    GArgs g{}; g.A = hs; g.B1 = sw2b; g.Out = y;
    g.rows_of = rows_of; g.probs = probs; g.eo = eo;
    k_gemm<3><<<dim3(NT / 128, CD / 128, 1), 256, 0, stream>>>(g);
  }
}

// Round 3
// 430.978 us; speedup vs baseline: 1.3406x; 1.3195x over previous
//
#include <hip/hip_runtime.h>

#define DEVI __device__ __forceinline__

typedef __attribute__((ext_vector_type(4))) float f32x4;
typedef __attribute__((ext_vector_type(8))) short bf16x8;

static constexpr int NT = 2048;   // tokens
static constexpr int CD = 2048;   // model dim
static constexpr int NE = 8;      // experts
static constexpr int ID = 1408;   // expert ffn dim
static constexpr int SD = 2816;   // shared ffn dim
static constexpr int ROWS = 2 * NT;
static constexpr int ROWS_PAD = ROWS + 128;

DEVI unsigned short f2bf(float f) {
  unsigned u = __builtin_bit_cast(unsigned, f);
  u += 0x7fff + ((u >> 16) & 1);           // RNE
  return (unsigned short)(u >> 16);
}
DEVI float bf2f(unsigned short s) { return __builtin_bit_cast(float, (unsigned)s << 16); }
DEVI float silu_f(float z) { return z / (1.f + __expf(-z)); }

DEVI void gll16(const void* g, void* l) {
  __builtin_amdgcn_global_load_lds((__attribute__((address_space(1))) void*)(void*)g,
                                   (__attribute__((address_space(3))) void*)l, 16, 0, 0);
}

DEVI void sync_step() {
  asm volatile("s_waitcnt vmcnt(0)" ::: "memory");
  __builtin_amdgcn_s_barrier();
  __builtin_amdgcn_sched_barrier(0);
}

// bijective XCD-chunk swizzle: within each 128-block super-chunk, dispatch ids
// on XCD k (id%8==k) get a contiguous 16-block (one-panel) range of work.
DEVI int swz_chunk(int bid, int nwg) {
  constexpr int CH = 16, G = 8 * CH;
  int nfull = nwg - (nwg % G);
  if (bid >= nfull) return bid;
  int c = bid / G, r = bid % G;
  return c * G + (r % 8) * CH + (r / 8);
}

// ---------------- fp32 -> bf16 convert (vectorized, grid-stride) -----------
__global__ __launch_bounds__(256) void k_cvt(const float* __restrict__ s,
                                             unsigned short* __restrict__ d, int n8)
{
  int i = blockIdx.x * 256 + threadIdx.x;
  int stride = gridDim.x * 256;
  for (; i < n8; i += stride) {
    float4 a = ((const float4*)s)[2 * i];
    float4 b = ((const float4*)s)[2 * i + 1];
    ushort4 p0 = make_ushort4(f2bf(a.x), f2bf(a.y), f2bf(a.z), f2bf(a.w));
    ushort4 p1 = make_ushort4(f2bf(b.x), f2bf(b.y), f2bf(b.z), f2bf(b.w));
    ((ushort4*)d)[2 * i]     = p0;
    ((ushort4*)d)[2 * i + 1] = p1;
  }
}

// ---------------- router ---------------------------------------------------
__global__ __launch_bounds__(64) void k_router(const float* __restrict__ x,
    const float* __restrict__ gw, int* __restrict__ counts,
    int* __restrict__ eidx, int* __restrict__ posn, float* __restrict__ probs)
{
  const int n = blockIdx.x;
  const int lane = threadIdx.x;
  const float4* xr = (const float4*)(x + (size_t)n * CD);
  float acc[NE];
#pragma unroll
  for (int e = 0; e < NE; ++e) acc[e] = 0.f;
  for (int i = lane; i < CD / 4; i += 64) {
    float4 xv = xr[i];
#pragma unroll
    for (int e = 0; e < NE; ++e) {
      float4 gv = ((const float4*)(gw + (size_t)e * CD))[i];
      acc[e] += xv.x * gv.x + xv.y * gv.y + xv.z * gv.z + xv.w * gv.w;
    }
  }
#pragma unroll
  for (int e = 0; e < NE; ++e) {
    float v = acc[e];
#pragma unroll
    for (int off = 32; off > 0; off >>= 1) v += __shfl_down(v, off);
    acc[e] = v;
  }
  if (lane == 0) {
    int b0 = 0; float m0 = acc[0];
#pragma unroll
    for (int e = 1; e < NE; ++e) if (acc[e] > m0) { m0 = acc[e]; b0 = e; }
    int b1 = -1; float m1 = 0.f;
#pragma unroll
    for (int e = 0; e < NE; ++e) {
      if (e == b0) continue;
      if (b1 < 0 || acc[e] > m1) { m1 = acc[e]; b1 = e; }
    }
    float d = __expf(m1 - m0);
    float inv = 1.f / (1.f + d);
    eidx[2 * n] = b0; eidx[2 * n + 1] = b1;
    probs[2 * n] = inv; probs[2 * n + 1] = d * inv;
    posn[2 * n] = atomicAdd(&counts[b0], 1);
    posn[2 * n + 1] = atomicAdd(&counts[b1], 1);
  }
}

__global__ void k_scan(const int* __restrict__ counts, int* __restrict__ bases) {
  if (threadIdx.x == 0) {
    int s = 0;
    for (int e = 0; e < NE; ++e) { bases[e] = s; s += counts[e]; }
  }
}

__global__ __launch_bounds__(256) void k_build(const int* __restrict__ eidx,
    const int* __restrict__ posn, const int* __restrict__ bases,
    int* __restrict__ rows_of, int* __restrict__ row2tok)
{
  int n = blockIdx.x * 256 + threadIdx.x;
  if (n >= NT) return;
#pragma unroll
  for (int k = 0; k < 2; ++k) {
    int e = eidx[2 * n + k];
    int row = bases[e] + posn[2 * n + k];
    rows_of[2 * n + k] = row;
    row2tok[row] = n;
  }
}

// ---------------- MFMA GEMM: dbuf LDS, prefetch-before-compute 2-phase ------
// O = A @ B^T. BM=128, BK=64, 4 waves (2x2). Per step: STAGE(next) issue;
// ds_read+MFMA(cur); s_waitcnt vmcnt(0); s_barrier.  XOR-swizzled LDS
// (linear gll16 dest + pre-swizzled global source + swizzled ds_read).
struct GArgs {
  const unsigned short* A;
  const unsigned short* B1; const unsigned short* B3;
  void* Out;
  const int* counts; const int* bases; const int* row2tok;
  const int* rows_of; const float* probs; const unsigned short* eo;
};

template<int MODE>
__global__ __launch_bounds__(256) void k_gemm(GArgs a)
{
  constexpr bool DUAL = (MODE == 0 || MODE == 2);
  constexpr int KD = (MODE == 0 || MODE == 2) ? CD : (MODE == 1 ? ID : SD);
  constexpr int BN = DUAL ? 64 : 128;
  constexpr int NH = BN / 2;        // per-wave col extent
  constexpr int NFT = NH / 16;
  constexpr int BT = DUAL ? 2 : 4;  // B staging instrs per wave per matrix
  constexpr int NMB = NT / 128;
  constexpr int NPN = (MODE == 0) ? ID / 64 : (MODE == 2) ? SD / 64 : CD / 128;
  constexpr int NWG = NMB * NPN * ((MODE <= 1) ? NE : 1);
  constexpr int NSTEP = KD / 64;    // 32 / 22 / 32 / 44 — all even

  __shared__ __align__(16) char sm[2][32768];

  int lin = swz_chunk((int)blockIdx.x, NWG);
  const int mx = lin % NMB; lin /= NMB;
  const int pn = lin % NPN;
  const int e  = lin / NPN;

  int M, baserow = 0;
  if constexpr (MODE <= 1) {
    int ne = a.counts[e];
    if (mx * 128 >= ne) return;
    M = ne; baserow = a.bases[e];
  } else { M = NT; }
  const int m0 = mx * 128;
  const int n0 = pn * BN;

  const unsigned short* B1;
  const unsigned short* B3 = nullptr;
  if constexpr (MODE == 0)      { B1 = a.B1 + ((size_t)e * ID + n0) * CD; B3 = a.B3 + ((size_t)e * ID + n0) * CD; }
  else if constexpr (MODE == 1) { B1 = a.B1 + ((size_t)e * CD + n0) * ID; }
  else if constexpr (MODE == 2) { B1 = a.B1 + (size_t)n0 * CD; B3 = a.B3 + (size_t)n0 * CD; }
  else                          { B1 = a.B1 + (size_t)n0 * SD; }

  const int tid = threadIdx.x, l = tid & 63, w = tid >> 6;
  const int wr = w >> 1, wc = w & 1;
  const int slot = ((l & 7) ^ ((l >> 3) & 7)) * 16;   // pre-swizzled global slot

  const char* aP[4];
#pragma unroll
  for (int t = 0; t < 4; ++t) {
    int r = w * 32 + t * 8 + (l >> 3);
    const unsigned short* rb;
    if constexpr (MODE == 0) {
      int grow = m0 + r; int gr = grow < M ? grow : 0;
      rb = a.A + (size_t)a.row2tok[baserow + gr] * CD;
    } else if constexpr (MODE == 1) {
      rb = a.A + (size_t)(baserow + m0 + r) * KD;
    } else {
      rb = a.A + (size_t)(m0 + r) * KD;
    }
    aP[t] = (const char*)rb + slot;
  }
  const char* bP1[BT]; const char* bP3[BT];
#pragma unroll
  for (int t = 0; t < BT; ++t) {
    int r = w * (8 * BT) + t * 8 + (l >> 3);
    bP1[t] = (const char*)(B1 + (size_t)r * KD) + slot;
    if constexpr (DUAL) bP3[t] = (const char*)(B3 + (size_t)r * KD) + slot;
  }

  f32x4 acc1[4][NFT]; f32x4 acc3[4][NFT];
#pragma unroll
  for (int m = 0; m < 4; ++m)
#pragma unroll
    for (int n = 0; n < NFT; ++n) {
      acc1[m][n] = {0.f, 0.f, 0.f, 0.f};
      if constexpr (DUAL) acc3[m][n] = {0.f, 0.f, 0.f, 0.f};
    }

  const int lrow = l & 15, lkg = l >> 4, l7 = l & 7;
  const int ao0 = (lkg ^ l7) * 16;
  const int ao1 = ((4 + lkg) ^ l7) * 16;

  auto stageF = [&](char* base, size_t kb) {
    char* sA = base; char* sB1 = base + 16384; char* sB3 = base + 24576;
#pragma unroll
    for (int t = 0; t < 4; ++t) gll16(aP[t] + kb, sA + (w * 4 + t) * 1024);
#pragma unroll
    for (int t = 0; t < BT; ++t) {
      gll16(bP1[t] + kb, sB1 + (w * BT + t) * 1024);
      if constexpr (DUAL) gll16(bP3[t] + kb, sB3 + (w * BT + t) * 1024);
    }
  };
  auto computeF = [&](const char* base) {
    const char* sA = base; const char* sB1 = base + 16384; const char* sB3 = base + 24576;
#pragma unroll
    for (int kk = 0; kk < 2; ++kk) {
      const int ao = kk ? ao1 : ao0;
      bf16x8 af[4];
#pragma unroll
      for (int m = 0; m < 4; ++m)
        af[m] = *(const bf16x8*)(sA + (wr * 64 + m * 16 + lrow) * 128 + ao);
#pragma unroll
      for (int n = 0; n < NFT; ++n) {
        bf16x8 b1 = *(const bf16x8*)(sB1 + (wc * NH + n * 16 + lrow) * 128 + ao);
        bf16x8 b3;
        if constexpr (DUAL)
          b3 = *(const bf16x8*)(sB3 + (wc * NH + n * 16 + lrow) * 128 + ao);
#pragma unroll
        for (int m = 0; m < 4; ++m) {
          acc1[m][n] = __builtin_amdgcn_mfma_f32_16x16x32_bf16(af[m], b1, acc1[m][n], 0, 0, 0);
          if constexpr (DUAL)
            acc3[m][n] = __builtin_amdgcn_mfma_f32_16x16x32_bf16(af[m], b3, acc3[m][n], 0, 0, 0);
        }
      }
    }
  };

  // prologue
  stageF(sm[0], 0);
  sync_step();
  // main loop, unrolled x2 for static dbuf indexing; NSTEP is even
  int t = 0;
  for (; t + 2 < NSTEP; t += 2) {
    stageF(sm[1], (size_t)(t + 1) * 128);
    computeF(sm[0]);
    sync_step();
    stageF(sm[0], (size_t)(t + 2) * 128);
    computeF(sm[1]);
    sync_step();
  }
  // tail: t == NSTEP-2
  stageF(sm[1], (size_t)(NSTEP - 1) * 128);
  computeF(sm[0]);
  sync_step();
  computeF(sm[1]);

  // epilogue (C/D: col = lane&15, row = (lane>>4)*4 + reg)
#pragma unroll
  for (int m = 0; m < 4; ++m) {
    int rbase = m0 + wr * 64 + m * 16 + lkg * 4;
#pragma unroll
    for (int j = 0; j < 4; ++j) {
      int grow = rbase + j;
      if constexpr (MODE <= 1) { if (grow >= M) continue; }
      int r0 = 0, r1 = 0; float p0 = 0.f, p1 = 0.f;
      if constexpr (MODE == 3) {
        r0 = a.rows_of[2 * grow]; r1 = a.rows_of[2 * grow + 1];
        p0 = a.probs[2 * grow];   p1 = a.probs[2 * grow + 1];
      }
#pragma unroll
      for (int n = 0; n < NFT; ++n) {
        int gcol = n0 + wc * NH + n * 16 + lrow;
        float v1 = acc1[m][n][j];
        if constexpr (MODE == 0) {
          float hh = silu_f(v1) * acc3[m][n][j];
          ((unsigned short*)a.Out)[(size_t)(baserow + grow) * ID + gcol] = f2bf(hh);
        } else if constexpr (MODE == 1) {
          ((unsigned short*)a.Out)[(size_t)(baserow + grow) * CD + gcol] = f2bf(v1);
        } else if constexpr (MODE == 2) {
          float hh = silu_f(v1) * acc3[m][n][j];
          ((unsigned short*)a.Out)[(size_t)grow * SD + gcol] = f2bf(hh);
        } else {
          float vv = v1 + p0 * bf2f(a.eo[(size_t)r0 * CD + gcol]) + p1 * bf2f(a.eo[(size_t)r1 * CD + gcol]);
          ((float*)a.Out)[(size_t)grow * CD + gcol] = vv;
        }
      }
    }
  }
}

// ---------------- launch ---------------------------------------------------
extern "C" void kernel_launch(void* const* d_in, const int* in_sizes, int n_in,
                              void* d_out, int out_size, void* d_ws, size_t ws_size,
                              hipStream_t stream)
{
  const float* x   = (const float*)d_in[0];
  const float* gw  = (const float*)d_in[1];
  const float* w1  = (const float*)d_in[2];
  const float* w3  = (const float*)d_in[3];
  const float* w2  = (const float*)d_in[4];
  const float* sw1 = (const float*)d_in[5];
  const float* sw3 = (const float*)d_in[6];
  const float* sw2 = (const float*)d_in[7];
  float* y = (float*)d_out;

  char* p = (char*)d_ws;
  auto alloc = [&](size_t b) { char* r = p; p += (b + 255) & ~(size_t)255; return r; };
  int*   counts  = (int*)alloc(NE * 4);
  int*   bases   = (int*)alloc(NE * 4);
  int*   eidx    = (int*)alloc((size_t)NT * 2 * 4);
  int*   posn    = (int*)alloc((size_t)NT * 2 * 4);
  float* probs   = (float*)alloc((size_t)NT * 2 * 4);
  int*   rows_of = (int*)alloc((size_t)NT * 2 * 4);
  int*   row2tok = (int*)alloc((size_t)ROWS * 4);
  unsigned short* xb   = (unsigned short*)alloc((size_t)NT * CD * 2);
  unsigned short* w1b  = (unsigned short*)alloc((size_t)NE * ID * CD * 2);
  unsigned short* w3b  = (unsigned short*)alloc((size_t)NE * ID * CD * 2);
  unsigned short* w2b  = (unsigned short*)alloc((size_t)NE * CD * ID * 2);
  unsigned short* sw1b = (unsigned short*)alloc((size_t)SD * CD * 2);
  unsigned short* sw3b = (unsigned short*)alloc((size_t)SD * CD * 2);
  unsigned short* sw2b = (unsigned short*)alloc((size_t)CD * SD * 2);
  unsigned short* h    = (unsigned short*)alloc((size_t)ROWS_PAD * ID * 2);
  unsigned short* eo   = (unsigned short*)alloc((size_t)ROWS_PAD * CD * 2);
  unsigned short* hs   = (unsigned short*)alloc((size_t)NT * SD * 2);

  hipMemsetAsync(counts, 0, NE * 4, stream);

  auto cvt = [&](const float* s, unsigned short* d, size_t n) {
    int n8 = (int)(n / 8);
    int grid = (n8 + 255) / 256; if (grid > 2048) grid = 2048;
    k_cvt<<<grid, 256, 0, stream>>>(s, d, n8);
  };
  cvt(x,   xb,   (size_t)NT * CD);
  cvt(w1,  w1b,  (size_t)NE * ID * CD);
  cvt(w3,  w3b,  (size_t)NE * ID * CD);
  cvt(w2,  w2b,  (size_t)NE * CD * ID);
  cvt(sw1, sw1b, (size_t)SD * CD);
  cvt(sw3, sw3b, (size_t)SD * CD);
  cvt(sw2, sw2b, (size_t)CD * SD);

  k_router<<<NT, 64, 0, stream>>>(x, gw, counts, eidx, posn, probs);
  k_scan<<<1, 64, 0, stream>>>(counts, bases);
  k_build<<<NT / 256, 256, 0, stream>>>(eidx, posn, bases, rows_of, row2tok);

  {
    GArgs g{}; g.A = xb; g.B1 = sw1b; g.B3 = sw3b; g.Out = hs;
    k_gemm<2><<<(NT / 128) * (SD / 64), 256, 0, stream>>>(g);
  }
  {
    GArgs g{}; g.A = xb; g.B1 = w1b; g.B3 = w3b; g.Out = h;
    g.counts = counts; g.bases = bases; g.row2tok = row2tok;
    k_gemm<0><<<(NT / 128) * (ID / 64) * NE, 256, 0, stream>>>(g);
  }
  {
    GArgs g{}; g.A = h; g.B1 = w2b; g.Out = eo;
    g.counts = counts; g.bases = bases;
    k_gemm<1><<<(NT / 128) * (CD / 128) * NE, 256, 0, stream>>>(g);
  }
  {
    GArgs g{}; g.A = hs; g.B1 = sw2b; g.Out = y;
    g.rows_of = rows_of; g.probs = probs; g.eo = eo;
    k_gemm<3><<<(NT / 128) * (CD / 128), 256, 0, stream>>>(g);
  }
}

// Round 4
// 401.196 us; speedup vs baseline: 1.4402x; 1.0742x over previous
//
#include <hip/hip_runtime.h>

#define DEVI __device__ __forceinline__

typedef __attribute__((ext_vector_type(4))) float f32x4;
typedef __attribute__((ext_vector_type(8))) short bf16x8;

static constexpr int NT = 2048;   // tokens
static constexpr int CD = 2048;   // model dim
static constexpr int NE = 8;      // experts
static constexpr int ID = 1408;   // expert ffn dim
static constexpr int SD = 2816;   // shared ffn dim
static constexpr int ROWS = 2 * NT;
static constexpr int ROWS_PAD = ROWS + 128;

DEVI unsigned short f2bf(float f) {
  unsigned u = __builtin_bit_cast(unsigned, f);
  u += 0x7fff + ((u >> 16) & 1);           // RNE
  return (unsigned short)(u >> 16);
}
DEVI float bf2f(unsigned short s) { return __builtin_bit_cast(float, (unsigned)s << 16); }
DEVI float silu_f(float z) { return z / (1.f + __expf(-z)); }

DEVI void gll16(const void* g, void* l) {
  __builtin_amdgcn_global_load_lds((__attribute__((address_space(1))) void*)(void*)g,
                                   (__attribute__((address_space(3))) void*)l, 16, 0, 0);
}

DEVI void bar_sched() {
  __builtin_amdgcn_s_barrier();
  __builtin_amdgcn_sched_barrier(0);
}
DEVI void wait_vm8() { asm volatile("s_waitcnt vmcnt(8)" ::: "memory"); }
DEVI void wait_vm0() { asm volatile("s_waitcnt vmcnt(0)" ::: "memory"); }
DEVI void wait_lgk0() { asm volatile("s_waitcnt lgkmcnt(0)" ::: "memory"); }

// bijective XCD-chunk swizzle: within each 128-block super-chunk, dispatch ids
// on XCD k (id%8==k) get a contiguous 16-block (one-panel) range of work.
DEVI int swz_chunk(int bid, int nwg) {
  constexpr int CH = 16, G = 8 * CH;
  int nfull = nwg - (nwg % G);
  if (bid >= nfull) return bid;
  int c = bid / G, r = bid % G;
  return c * G + (r % 8) * CH + (r / 8);
}

// ---------------- fp32 -> bf16 convert (vectorized, grid-stride) -----------
__global__ __launch_bounds__(256) void k_cvt(const float* __restrict__ s,
                                             unsigned short* __restrict__ d, int n8)
{
  int i = blockIdx.x * 256 + threadIdx.x;
  int stride = gridDim.x * 256;
  for (; i < n8; i += stride) {
    float4 a = ((const float4*)s)[2 * i];
    float4 b = ((const float4*)s)[2 * i + 1];
    ushort4 p0 = make_ushort4(f2bf(a.x), f2bf(a.y), f2bf(a.z), f2bf(a.w));
    ushort4 p1 = make_ushort4(f2bf(b.x), f2bf(b.y), f2bf(b.z), f2bf(b.w));
    ((ushort4*)d)[2 * i]     = p0;
    ((ushort4*)d)[2 * i + 1] = p1;
  }
}

// ---------------- router ---------------------------------------------------
__global__ __launch_bounds__(64) void k_router(const float* __restrict__ x,
    const float* __restrict__ gw, int* __restrict__ counts,
    int* __restrict__ eidx, int* __restrict__ posn, float* __restrict__ probs)
{
  const int n = blockIdx.x;
  const int lane = threadIdx.x;
  const float4* xr = (const float4*)(x + (size_t)n * CD);
  float acc[NE];
#pragma unroll
  for (int e = 0; e < NE; ++e) acc[e] = 0.f;
  for (int i = lane; i < CD / 4; i += 64) {
    float4 xv = xr[i];
#pragma unroll
    for (int e = 0; e < NE; ++e) {
      float4 gv = ((const float4*)(gw + (size_t)e * CD))[i];
      acc[e] += xv.x * gv.x + xv.y * gv.y + xv.z * gv.z + xv.w * gv.w;
    }
  }
#pragma unroll
  for (int e = 0; e < NE; ++e) {
    float v = acc[e];
#pragma unroll
    for (int off = 32; off > 0; off >>= 1) v += __shfl_down(v, off);
    acc[e] = v;
  }
  if (lane == 0) {
    int b0 = 0; float m0 = acc[0];
#pragma unroll
    for (int e = 1; e < NE; ++e) if (acc[e] > m0) { m0 = acc[e]; b0 = e; }
    int b1 = -1; float m1 = 0.f;
#pragma unroll
    for (int e = 0; e < NE; ++e) {
      if (e == b0) continue;
      if (b1 < 0 || acc[e] > m1) { m1 = acc[e]; b1 = e; }
    }
    float d = __expf(m1 - m0);
    float inv = 1.f / (1.f + d);
    eidx[2 * n] = b0; eidx[2 * n + 1] = b1;
    probs[2 * n] = inv; probs[2 * n + 1] = d * inv;
    posn[2 * n] = atomicAdd(&counts[b0], 1);
    posn[2 * n + 1] = atomicAdd(&counts[b1], 1);
  }
}

__global__ void k_scan(const int* __restrict__ counts, int* __restrict__ bases) {
  if (threadIdx.x == 0) {
    int s = 0;
    for (int e = 0; e < NE; ++e) { bases[e] = s; s += counts[e]; }
  }
}

__global__ __launch_bounds__(256) void k_build(const int* __restrict__ eidx,
    const int* __restrict__ posn, const int* __restrict__ bases,
    int* __restrict__ rows_of, int* __restrict__ row2tok)
{
  int n = blockIdx.x * 256 + threadIdx.x;
  if (n >= NT) return;
#pragma unroll
  for (int k = 0; k < 2; ++k) {
    int e = eidx[2 * n + k];
    int row = bases[e] + posn[2 * n + k];
    rows_of[2 * n + k] = row;
    row2tok[row] = n;
  }
}

// ---------------- MFMA GEMM: dbuf LDS + counted-vmcnt async pipeline --------
// O = A @ B^T. BM=128, BK=64, 4 waves (2x2). Per K-step:
//   stage(nxt) [8 gll16/wave]; vmcnt(8) [drains PREV stage only]; barrier;
//   ds_read+MFMA(cur); lgkmcnt(0); barrier.
// XOR-swizzled LDS (linear gll16 dest + pre-swizzled global src + swz ds_read).
struct GArgs {
  const unsigned short* A;
  const unsigned short* B1; const unsigned short* B3;
  void* Out;
  const int* counts; const int* bases; const int* row2tok;
  const int* rows_of; const float* probs; const unsigned short* eo;
};

template<int MODE>
__global__ __launch_bounds__(256) void k_gemm(GArgs a)
{
  constexpr bool DUAL = (MODE == 0 || MODE == 2);
  constexpr int KD = (MODE == 0 || MODE == 2) ? CD : (MODE == 1 ? ID : SD);
  constexpr int BN = DUAL ? 64 : 128;
  constexpr int NH = BN / 2;        // per-wave col extent
  constexpr int NFT = NH / 16;
  constexpr int BT = DUAL ? 2 : 4;  // B staging instrs per wave per matrix
  constexpr int NMB = NT / 128;
  constexpr int NPN = (MODE == 0) ? ID / 64 : (MODE == 2) ? SD / 64 : CD / 128;
  constexpr int NWG = NMB * NPN * ((MODE <= 1) ? NE : 1);
  constexpr int NSTEP = KD / 64;    // 32 / 22 / 32 / 44 — all even

  __shared__ __align__(16) char sm[2][32768];

  int lin = swz_chunk((int)blockIdx.x, NWG);
  const int mx = lin % NMB; lin /= NMB;
  const int pn = lin % NPN;
  const int e  = lin / NPN;

  int M, baserow = 0;
  if constexpr (MODE <= 1) {
    int ne = a.counts[e];
    if (mx * 128 >= ne) return;
    M = ne; baserow = a.bases[e];
  } else { M = NT; }
  const int m0 = mx * 128;
  const int n0 = pn * BN;

  const unsigned short* B1;
  const unsigned short* B3 = nullptr;
  if constexpr (MODE == 0)      { B1 = a.B1 + ((size_t)e * ID + n0) * CD; B3 = a.B3 + ((size_t)e * ID + n0) * CD; }
  else if constexpr (MODE == 1) { B1 = a.B1 + ((size_t)e * CD + n0) * ID; }
  else if constexpr (MODE == 2) { B1 = a.B1 + (size_t)n0 * CD; B3 = a.B3 + (size_t)n0 * CD; }
  else                          { B1 = a.B1 + (size_t)n0 * SD; }

  const int tid = threadIdx.x, l = tid & 63, w = tid >> 6;
  const int wr = w >> 1, wc = w & 1;
  const int slot = ((l & 7) ^ ((l >> 3) & 7)) * 16;   // pre-swizzled global slot

  const char* aP[4];
#pragma unroll
  for (int t = 0; t < 4; ++t) {
    int r = w * 32 + t * 8 + (l >> 3);
    const unsigned short* rb;
    if constexpr (MODE == 0) {
      int grow = m0 + r; int gr = grow < M ? grow : 0;
      rb = a.A + (size_t)a.row2tok[baserow + gr] * CD;
    } else if constexpr (MODE == 1) {
      rb = a.A + (size_t)(baserow + m0 + r) * KD;
    } else {
      rb = a.A + (size_t)(m0 + r) * KD;
    }
    aP[t] = (const char*)rb + slot;
  }
  const char* bP1[BT]; const char* bP3[BT];
#pragma unroll
  for (int t = 0; t < BT; ++t) {
    int r = w * (8 * BT) + t * 8 + (l >> 3);
    bP1[t] = (const char*)(B1 + (size_t)r * KD) + slot;
    if constexpr (DUAL) bP3[t] = (const char*)(B3 + (size_t)r * KD) + slot;
  }

  f32x4 acc1[4][NFT]; f32x4 acc3[4][NFT];
#pragma unroll
  for (int m = 0; m < 4; ++m)
#pragma unroll
    for (int n = 0; n < NFT; ++n) {
      acc1[m][n] = {0.f, 0.f, 0.f, 0.f};
      if constexpr (DUAL) acc3[m][n] = {0.f, 0.f, 0.f, 0.f};
    }

  const int lrow = l & 15, lkg = l >> 4, l7 = l & 7;
  const int ao0 = (lkg ^ l7) * 16;
  const int ao1 = ((4 + lkg) ^ l7) * 16;

  auto stageF = [&](char* base, size_t kb) {
    char* sA = base; char* sB1 = base + 16384; char* sB3 = base + 24576;
#pragma unroll
    for (int t = 0; t < 4; ++t) gll16(aP[t] + kb, sA + (w * 4 + t) * 1024);
#pragma unroll
    for (int t = 0; t < BT; ++t) {
      gll16(bP1[t] + kb, sB1 + (w * BT + t) * 1024);
      if constexpr (DUAL) gll16(bP3[t] + kb, sB3 + (w * BT + t) * 1024);
    }
  };
  auto computeF = [&](const char* base) {
    const char* sA = base; const char* sB1 = base + 16384; const char* sB3 = base + 24576;
#pragma unroll
    for (int kk = 0; kk < 2; ++kk) {
      const int ao = kk ? ao1 : ao0;
      bf16x8 af[4];
#pragma unroll
      for (int m = 0; m < 4; ++m)
        af[m] = *(const bf16x8*)(sA + (wr * 64 + m * 16 + lrow) * 128 + ao);
#pragma unroll
      for (int n = 0; n < NFT; ++n) {
        bf16x8 b1 = *(const bf16x8*)(sB1 + (wc * NH + n * 16 + lrow) * 128 + ao);
        bf16x8 b3;
        if constexpr (DUAL)
          b3 = *(const bf16x8*)(sB3 + (wc * NH + n * 16 + lrow) * 128 + ao);
#pragma unroll
        for (int m = 0; m < 4; ++m) {
          acc1[m][n] = __builtin_amdgcn_mfma_f32_16x16x32_bf16(af[m], b1, acc1[m][n], 0, 0, 0);
          if constexpr (DUAL)
            acc3[m][n] = __builtin_amdgcn_mfma_f32_16x16x32_bf16(af[m], b3, acc3[m][n], 0, 0, 0);
        }
      }
    }
  };

  // ---- counted-vmcnt double-buffered pipeline (NSTEP even) ----
  stageF(sm[0], 0);
  int t = 0;
  for (; t < NSTEP - 2; t += 2) {
    stageF(sm[1], (size_t)(t + 1) * 128);
    wait_vm8(); bar_sched();
    computeF(sm[0]);
    wait_lgk0(); bar_sched();
    stageF(sm[0], (size_t)(t + 2) * 128);
    wait_vm8(); bar_sched();
    computeF(sm[1]);
    wait_lgk0(); bar_sched();
  }
  // tail: t == NSTEP-2
  stageF(sm[1], (size_t)(NSTEP - 1) * 128);
  wait_vm8(); bar_sched();
  computeF(sm[0]);
  wait_vm0(); bar_sched();
  computeF(sm[1]);

  // epilogue (C/D: col = lane&15, row = (lane>>4)*4 + reg)
#pragma unroll
  for (int m = 0; m < 4; ++m) {
    int rbase = m0 + wr * 64 + m * 16 + lkg * 4;
#pragma unroll
    for (int j = 0; j < 4; ++j) {
      int grow = rbase + j;
      if constexpr (MODE <= 1) { if (grow >= M) continue; }
      int r0 = 0, r1 = 0; float p0 = 0.f, p1 = 0.f;
      if constexpr (MODE == 3) {
        r0 = a.rows_of[2 * grow]; r1 = a.rows_of[2 * grow + 1];
        p0 = a.probs[2 * grow];   p1 = a.probs[2 * grow + 1];
      }
#pragma unroll
      for (int n = 0; n < NFT; ++n) {
        int gcol = n0 + wc * NH + n * 16 + lrow;
        float v1 = acc1[m][n][j];
        if constexpr (MODE == 0) {
          float hh = silu_f(v1) * acc3[m][n][j];
          ((unsigned short*)a.Out)[(size_t)(baserow + grow) * ID + gcol] = f2bf(hh);
        } else if constexpr (MODE == 1) {
          ((unsigned short*)a.Out)[(size_t)(baserow + grow) * CD + gcol] = f2bf(v1);
        } else if constexpr (MODE == 2) {
          float hh = silu_f(v1) * acc3[m][n][j];
          ((unsigned short*)a.Out)[(size_t)grow * SD + gcol] = f2bf(hh);
        } else {
          float vv = v1 + p0 * bf2f(a.eo[(size_t)r0 * CD + gcol]) + p1 * bf2f(a.eo[(size_t)r1 * CD + gcol]);
          ((float*)a.Out)[(size_t)grow * CD + gcol] = vv;
        }
      }
    }
  }
}

// ---------------- launch ---------------------------------------------------
extern "C" void kernel_launch(void* const* d_in, const int* in_sizes, int n_in,
                              void* d_out, int out_size, void* d_ws, size_t ws_size,
                              hipStream_t stream)
{
  const float* x   = (const float*)d_in[0];
  const float* gw  = (const float*)d_in[1];
  const float* w1  = (const float*)d_in[2];
  const float* w3  = (const float*)d_in[3];
  const float* w2  = (const float*)d_in[4];
  const float* sw1 = (const float*)d_in[5];
  const float* sw3 = (const float*)d_in[6];
  const float* sw2 = (const float*)d_in[7];
  float* y = (float*)d_out;

  char* p = (char*)d_ws;
  auto alloc = [&](size_t b) { char* r = p; p += (b + 255) & ~(size_t)255; return r; };
  int*   counts  = (int*)alloc(NE * 4);
  int*   bases   = (int*)alloc(NE * 4);
  int*   eidx    = (int*)alloc((size_t)NT * 2 * 4);
  int*   posn    = (int*)alloc((size_t)NT * 2 * 4);
  float* probs   = (float*)alloc((size_t)NT * 2 * 4);
  int*   rows_of = (int*)alloc((size_t)NT * 2 * 4);
  int*   row2tok = (int*)alloc((size_t)ROWS * 4);
  unsigned short* xb   = (unsigned short*)alloc((size_t)NT * CD * 2);
  unsigned short* w1b  = (unsigned short*)alloc((size_t)NE * ID * CD * 2);
  unsigned short* w3b  = (unsigned short*)alloc((size_t)NE * ID * CD * 2);
  unsigned short* w2b  = (unsigned short*)alloc((size_t)NE * CD * ID * 2);
  unsigned short* sw1b = (unsigned short*)alloc((size_t)SD * CD * 2);
  unsigned short* sw3b = (unsigned short*)alloc((size_t)SD * CD * 2);
  unsigned short* sw2b = (unsigned short*)alloc((size_t)CD * SD * 2);
  unsigned short* h    = (unsigned short*)alloc((size_t)ROWS_PAD * ID * 2);
  unsigned short* eo   = (unsigned short*)alloc((size_t)ROWS_PAD * CD * 2);
  unsigned short* hs   = (unsigned short*)alloc((size_t)NT * SD * 2);

  hipMemsetAsync(counts, 0, NE * 4, stream);

  auto cvt = [&](const float* s, unsigned short* d, size_t n) {
    int n8 = (int)(n / 8);
    int grid = (n8 + 255) / 256; if (grid > 2048) grid = 2048;
    k_cvt<<<grid, 256, 0, stream>>>(s, d, n8);
  };
  cvt(x,   xb,   (size_t)NT * CD);
  cvt(w1,  w1b,  (size_t)NE * ID * CD);
  cvt(w3,  w3b,  (size_t)NE * ID * CD);
  cvt(w2,  w2b,  (size_t)NE * CD * ID);
  cvt(sw1, sw1b, (size_t)SD * CD);
  cvt(sw3, sw3b, (size_t)SD * CD);
  cvt(sw2, sw2b, (size_t)CD * SD);

  k_router<<<NT, 64, 0, stream>>>(x, gw, counts, eidx, posn, probs);
  k_scan<<<1, 64, 0, stream>>>(counts, bases);
  k_build<<<NT / 256, 256, 0, stream>>>(eidx, posn, bases, rows_of, row2tok);

  {
    GArgs g{}; g.A = xb; g.B1 = sw1b; g.B3 = sw3b; g.Out = hs;
    k_gemm<2><<<(NT / 128) * (SD / 64), 256, 0, stream>>>(g);
  }
  {
    GArgs g{}; g.A = xb; g.B1 = w1b; g.B3 = w3b; g.Out = h;
    g.counts = counts; g.bases = bases; g.row2tok = row2tok;
    k_gemm<0><<<(NT / 128) * (ID / 64) * NE, 256, 0, stream>>>(g);
  }
  {
    GArgs g{}; g.A = h; g.B1 = w2b; g.Out = eo;
    g.counts = counts; g.bases = bases;
    k_gemm<1><<<(NT / 128) * (CD / 128) * NE, 256, 0, stream>>>(g);
  }
  {
    GArgs g{}; g.A = hs; g.B1 = sw2b; g.Out = y;
    g.rows_of = rows_of; g.probs = probs; g.eo = eo;
    k_gemm<3><<<(NT / 128) * (CD / 128), 256, 0, stream>>>(g);
  }
}